// Round 1
// baseline (28.162 us; speedup 1.0000x reference)
//
#include <hip/hip_runtime.h>
#include <math.h>

// Problem constants (match reference)
constexpr int B_ = 32, Q_ = 500, N_ = 200, K_ = 16, C_ = 92;
constexpr int TWO_K = 2 * K_;          // 32
constexpr int BQ = 8;                  // q-tile per block
constexpr int TPAD = 34;               // padded LDS row stride (floats) for targets
constexpr float CLASS_COST = 1.0f, POLY_COST = 5.0f, GIOU_COST = 1.0f;
constexpr float EPS_ = 1e-6f;

__global__ __launch_bounds__(256)
void matcher_cost_kernel(const float* __restrict__ logits,   // (B,Q,C)
                         const float* __restrict__ ppoly,    // (B,Q,K,2)
                         const int*   __restrict__ labels,   // (B,N)
                         const float* __restrict__ tpoly,    // (B,N,K,2)
                         float* __restrict__ out)            // (B,Q,N)
{
    __shared__ float sT[N_ * TPAD];     // target polylines, padded rows (27200 B)
    __shared__ float sTB[N_ * 5];       // target bboxes, pad 5 (4000 B)
    __shared__ int   sLbl[N_];          // labels (800 B)
    __shared__ float sProb[BQ * C_];    // logits -> probs in place (2944 B)
    __shared__ float sP[BQ * TWO_K];    // pred polylines tile (1024 B)

    const int tid  = threadIdx.x;
    const int qt   = blockIdx.x;        // q-tile index (0..62)
    const int b    = blockIdx.y;        // batch
    const int q0   = qt * BQ;
    const int qi   = tid >> 5;          // 0..7
    const int lane = tid & 31;
    const int q    = q0 + qi;
    const bool qvalid = (q < Q_);
    const int nq = min(BQ, Q_ - q0);

    // ---------------- stage to LDS ----------------
    {
        const float* tb_base = tpoly + (size_t)b * (N_ * TWO_K);
        // 1600 float4s, coalesced global, float2 LDS writes (8B aligned: 136n+8k)
        for (int u = tid; u < N_ * TWO_K / 4; u += 256) {
            float4 v = reinterpret_cast<const float4*>(tb_base)[u];
            int n = (u * 4) / TWO_K;
            int j = (u * 4) % TWO_K;
            float* d = &sT[n * TPAD + j];
            reinterpret_cast<float2*>(d)[0] = make_float2(v.x, v.y);
            reinterpret_cast<float2*>(d)[1] = make_float2(v.z, v.w);
        }
        for (int n = tid; n < N_; n += 256) sLbl[n] = labels[b * N_ + n];

        const float* pp_base = ppoly + ((size_t)(b * Q_ + q0)) * TWO_K;
        for (int u = tid; u < nq * TWO_K; u += 256) sP[u] = pp_base[u];

        const float* lg_base = logits + ((size_t)(b * Q_ + q0)) * C_;
        for (int u = tid; u < nq * C_; u += 256) sProb[u] = lg_base[u];
    }
    __syncthreads();

    // ---------------- target bboxes ----------------
    for (int n = tid; n < N_; n += 256) {
        const float2* tr = reinterpret_cast<const float2*>(&sT[n * TPAD]);
        float xm = INFINITY, ym = INFINITY, xM = -INFINITY, yM = -INFINITY;
        #pragma unroll
        for (int k = 0; k < K_; ++k) {
            float2 t = tr[k];
            xm = fminf(xm, t.x); xM = fmaxf(xM, t.x);
            ym = fminf(ym, t.y); yM = fmaxf(yM, t.y);
        }
        sTB[n * 5 + 0] = xm; sTB[n * 5 + 1] = ym;
        sTB[n * 5 + 2] = xM; sTB[n * 5 + 3] = yM;
    }

    // ---------------- softmax per q (32-lane groups) ----------------
    {
        float lv[3];
        float m = -INFINITY;
        #pragma unroll
        for (int j = 0; j < 3; ++j) {
            int c = lane + 32 * j;
            lv[j] = (qvalid && c < C_) ? sProb[qi * C_ + c] : -INFINITY;
            m = fmaxf(m, lv[j]);
        }
        #pragma unroll
        for (int off = 16; off; off >>= 1) m = fmaxf(m, __shfl_xor(m, off, 32));
        float s = 0.0f;
        #pragma unroll
        for (int j = 0; j < 3; ++j) {
            int c = lane + 32 * j;
            if (c < C_) { float e = __expf(lv[j] - m); lv[j] = e; s += e; }
        }
        #pragma unroll
        for (int off = 16; off; off >>= 1) s += __shfl_xor(s, off, 32);
        float rs = 1.0f / s;
        if (qvalid) {
            #pragma unroll
            for (int j = 0; j < 3; ++j) {
                int c = lane + 32 * j;
                if (c < C_) sProb[qi * C_ + c] = lv[j] * rs;  // each lane rewrites only what it read
            }
        }
    }

    // ---------------- pred polyline -> registers + bbox ----------------
    float2 pt[K_];
    float pxm = INFINITY, pym = INFINITY, pxM = -INFINITY, pyM = -INFINITY;
    if (qvalid) {
        const float4* pr = reinterpret_cast<const float4*>(&sP[qi * TWO_K]);
        #pragma unroll
        for (int j = 0; j < 8; ++j) {
            float4 v = pr[j];               // (x_{2j}, y_{2j}, x_{2j+1}, y_{2j+1})
            pt[2 * j]     = make_float2(v.x, v.y);
            pt[2 * j + 1] = make_float2(v.z, v.w);
            pxm = fminf(pxm, fminf(v.x, v.z));
            pxM = fmaxf(pxM, fmaxf(v.x, v.z));
            pym = fminf(pym, fminf(v.y, v.w));
            pyM = fmaxf(pyM, fmaxf(v.y, v.w));
        }
    }
    __syncthreads();   // sTB + sProb ready

    if (!qvalid) return;

    const float parea = (pxM - pxm) * (pyM - pym);
    float* outRow = out + ((size_t)(b * Q_ + q)) * N_;
    const float* probRow = &sProb[qi * C_];

    for (int i = 0; i < 7; ++i) {
        int n = lane + 32 * i;
        if (n >= N_) break;
        const float2* tr = reinterpret_cast<const float2*>(&sT[n * TPAD]);
        float fwd = 0.0f, rev = 0.0f;
        #pragma unroll
        for (int k = 0; k < K_; ++k) {
            float2 t = tr[k];                       // single LDS read, used twice
            float2 pf = pt[k];
            float2 pr = pt[K_ - 1 - k];             // reversed pred from registers
            fwd += fabsf(pf.x - t.x) + fabsf(pf.y - t.y);
            rev += fabsf(pr.x - t.x) + fabsf(pr.y - t.y);
        }
        float cpoly = fminf(fwd, rev) * (1.0f / 32.0f);

        float cclass = -probRow[sLbl[n]];

        float tx0 = sTB[n * 5 + 0], ty0 = sTB[n * 5 + 1];
        float tx1 = sTB[n * 5 + 2], ty1 = sTB[n * 5 + 3];
        float tarea = (tx1 - tx0) * (ty1 - ty0);
        float ix0 = fmaxf(pxm, tx0), iy0 = fmaxf(pym, ty0);
        float ix1 = fminf(pxM, tx1), iy1 = fminf(pyM, ty1);
        float iw = fmaxf(ix1 - ix0, 0.0f), ih = fmaxf(iy1 - iy0, 0.0f);
        float inter = iw * ih;
        float uni = parea + tarea - inter;
        float iou = inter / fmaxf(uni, EPS_);
        float cx0 = fminf(pxm, tx0), cy0 = fminf(pym, ty0);
        float cx1 = fmaxf(pxM, tx1), cy1 = fmaxf(pyM, ty1);
        float cw = fmaxf(cx1 - cx0, 0.0f), ch = fmaxf(cy1 - cy0, 0.0f);
        float ca = cw * ch;
        float giou = iou - (ca - uni) / fmaxf(ca, EPS_);

        outRow[n] = CLASS_COST * cclass + POLY_COST * cpoly - GIOU_COST * giou;
    }
}

extern "C" void kernel_launch(void* const* d_in, const int* in_sizes, int n_in,
                              void* d_out, int out_size, void* d_ws, size_t ws_size,
                              hipStream_t stream) {
    const float* logits = (const float*)d_in[0];   // (B,Q,C)
    const float* ppoly  = (const float*)d_in[1];   // (B,Q,K,2)
    const int*   labels = (const int*)d_in[2];     // (B,N)
    const float* tpoly  = (const float*)d_in[3];   // (B,N,K,2)
    float* out = (float*)d_out;                    // (B,Q,N)

    dim3 grid((Q_ + BQ - 1) / BQ, B_);             // (63, 32)
    matcher_cost_kernel<<<grid, 256, 0, stream>>>(logits, ppoly, labels, tpoly, out);
}

// Round 2
// 26.537 us; speedup vs baseline: 1.0612x; 1.0612x over previous
//
#include <hip/hip_runtime.h>
#include <math.h>

// Problem constants (match reference)
constexpr int B_ = 32, Q_ = 500, N_ = 200, K_ = 16, C_ = 92;
constexpr int TWO_K = 2 * K_;          // 32
constexpr int BQ = 16;                 // q-tile per block
constexpr int THREADS = 512;           // 8 waves/block
constexpr int TPAD = 34;               // padded LDS row stride (floats) for targets
constexpr float CLASS_COST = 1.0f, POLY_COST = 5.0f, GIOU_COST = 1.0f;
constexpr float EPS_ = 1e-6f;

__global__ __launch_bounds__(THREADS)
void matcher_cost_kernel(const float* __restrict__ logits,   // (B,Q,C)
                         const float* __restrict__ ppoly,    // (B,Q,K,2)
                         const int*   __restrict__ labels,   // (B,N)
                         const float* __restrict__ tpoly,    // (B,N,K,2)
                         float* __restrict__ out)            // (B,Q,N)
{
    __shared__ float sT[N_ * TPAD];     // target polylines, padded rows (27200 B)
    __shared__ float sTB[N_ * 5];       // target bbox(4) + area(1)     (4000 B)
    __shared__ int   sLbl[N_];          // labels                        (800 B)
    __shared__ float sProb[BQ * C_];    // logits -> probs in place     (5888 B)
    __shared__ float sP[BQ * TWO_K];    // pred polylines tile          (2048 B)
    // total ~39.9 KB -> 4 blocks/CU by LDS (32 waves/CU ceiling)

    const int tid  = threadIdx.x;
    const int qt   = blockIdx.x;        // q-tile index (0..31)
    const int b    = blockIdx.y;        // batch
    const int q0   = qt * BQ;
    const int qi   = tid >> 5;          // 0..15
    const int lane = tid & 31;
    const int q    = q0 + qi;
    const bool qvalid = (q < Q_);
    const int nq = min(BQ, Q_ - q0);

    // ---------------- stage to LDS ----------------
    {
        const float* tb_base = tpoly + (size_t)b * (N_ * TWO_K);
        // 1600 float4s, coalesced global, float2 LDS writes (8B aligned: 136n+8k)
        for (int u = tid; u < N_ * TWO_K / 4; u += THREADS) {
            float4 v = reinterpret_cast<const float4*>(tb_base)[u];
            int n = (u * 4) / TWO_K;
            int j = (u * 4) % TWO_K;
            float* d = &sT[n * TPAD + j];
            reinterpret_cast<float2*>(d)[0] = make_float2(v.x, v.y);
            reinterpret_cast<float2*>(d)[1] = make_float2(v.z, v.w);
        }
        for (int n = tid; n < N_; n += THREADS) sLbl[n] = labels[b * N_ + n];

        const float* pp_base = ppoly + ((size_t)(b * Q_ + q0)) * TWO_K;
        for (int u = tid; u < nq * TWO_K; u += THREADS) sP[u] = pp_base[u];

        const float* lg_base = logits + ((size_t)(b * Q_ + q0)) * C_;
        for (int u = tid; u < nq * C_; u += THREADS) sProb[u] = lg_base[u];
    }
    __syncthreads();

    // ---------------- target bboxes + area ----------------
    for (int n = tid; n < N_; n += THREADS) {
        const float2* tr = reinterpret_cast<const float2*>(&sT[n * TPAD]);
        float xm = INFINITY, ym = INFINITY, xM = -INFINITY, yM = -INFINITY;
        #pragma unroll
        for (int k = 0; k < K_; ++k) {
            float2 t = tr[k];
            xm = fminf(xm, t.x); xM = fmaxf(xM, t.x);
            ym = fminf(ym, t.y); yM = fmaxf(yM, t.y);
        }
        sTB[n * 5 + 0] = xm; sTB[n * 5 + 1] = ym;
        sTB[n * 5 + 2] = xM; sTB[n * 5 + 3] = yM;
        sTB[n * 5 + 4] = (xM - xm) * (yM - ym);   // tarea (clips unnecessary: M>=m)
    }

    // ---------------- softmax per q (32-lane groups) ----------------
    {
        float lv[3];
        float m = -INFINITY;
        #pragma unroll
        for (int j = 0; j < 3; ++j) {
            int c = lane + 32 * j;
            lv[j] = (qvalid && c < C_) ? sProb[qi * C_ + c] : -INFINITY;
            m = fmaxf(m, lv[j]);
        }
        #pragma unroll
        for (int off = 16; off; off >>= 1) m = fmaxf(m, __shfl_xor(m, off, 32));
        float s = 0.0f;
        #pragma unroll
        for (int j = 0; j < 3; ++j) {
            int c = lane + 32 * j;
            if (c < C_) { float e = __expf(lv[j] - m); lv[j] = e; s += e; }
        }
        #pragma unroll
        for (int off = 16; off; off >>= 1) s += __shfl_xor(s, off, 32);
        float rs = 1.0f / s;
        if (qvalid) {
            #pragma unroll
            for (int j = 0; j < 3; ++j) {
                int c = lane + 32 * j;
                if (c < C_) sProb[qi * C_ + c] = lv[j] * rs;  // each lane rewrites only what it read
            }
        }
    }

    // ---------------- pred polyline -> registers + bbox ----------------
    float2 pt[K_];
    float pxm = INFINITY, pym = INFINITY, pxM = -INFINITY, pyM = -INFINITY;
    if (qvalid) {
        const float4* pr = reinterpret_cast<const float4*>(&sP[qi * TWO_K]);
        #pragma unroll
        for (int j = 0; j < 8; ++j) {
            float4 v = pr[j];               // (x_{2j}, y_{2j}, x_{2j+1}, y_{2j+1})
            pt[2 * j]     = make_float2(v.x, v.y);
            pt[2 * j + 1] = make_float2(v.z, v.w);
            pxm = fminf(pxm, fminf(v.x, v.z));
            pxM = fmaxf(pxM, fmaxf(v.x, v.z));
            pym = fminf(pym, fminf(v.y, v.w));
            pyM = fmaxf(pyM, fmaxf(v.y, v.w));
        }
    }
    __syncthreads();   // sTB + sProb ready

    if (!qvalid) return;

    const float parea = (pxM - pxm) * (pyM - pym);
    float* outRow = out + ((size_t)(b * Q_ + q)) * N_;
    const float* probRow = &sProb[qi * C_];

    for (int i = 0; i < 7; ++i) {
        int n = lane + 32 * i;
        if (n >= N_) break;
        const float2* tr = reinterpret_cast<const float2*>(&sT[n * TPAD]);
        float fwd = 0.0f, rev = 0.0f;
        #pragma unroll
        for (int k = 0; k < K_; ++k) {
            float2 t = tr[k];                       // single LDS read, used twice
            float2 pf = pt[k];
            float2 pr = pt[K_ - 1 - k];             // reversed pred from registers
            fwd += fabsf(pf.x - t.x) + fabsf(pf.y - t.y);
            rev += fabsf(pr.x - t.x) + fabsf(pr.y - t.y);
        }
        float cpoly = fminf(fwd, rev) * (1.0f / 32.0f);

        float cclass = -probRow[sLbl[n]];

        float tx0 = sTB[n * 5 + 0], ty0 = sTB[n * 5 + 1];
        float tx1 = sTB[n * 5 + 2], ty1 = sTB[n * 5 + 3];
        float tarea = sTB[n * 5 + 4];
        float ix0 = fmaxf(pxm, tx0), iy0 = fmaxf(pym, ty0);
        float ix1 = fminf(pxM, tx1), iy1 = fminf(pyM, ty1);
        float iw = fmaxf(ix1 - ix0, 0.0f), ih = fmaxf(iy1 - iy0, 0.0f);
        float inter = iw * ih;
        float uni = parea + tarea - inter;
        float iou = inter / fmaxf(uni, EPS_);
        float cx0 = fminf(pxm, tx0), cy0 = fminf(pym, ty0);
        float cx1 = fmaxf(pxM, tx1), cy1 = fmaxf(pyM, ty1);
        float cw = fmaxf(cx1 - cx0, 0.0f), ch = fmaxf(cy1 - cy0, 0.0f);
        float ca = cw * ch;
        float giou = iou - (ca - uni) / fmaxf(ca, EPS_);

        outRow[n] = CLASS_COST * cclass + POLY_COST * cpoly - GIOU_COST * giou;
    }
}

extern "C" void kernel_launch(void* const* d_in, const int* in_sizes, int n_in,
                              void* d_out, int out_size, void* d_ws, size_t ws_size,
                              hipStream_t stream) {
    const float* logits = (const float*)d_in[0];   // (B,Q,C)
    const float* ppoly  = (const float*)d_in[1];   // (B,Q,K,2)
    const int*   labels = (const int*)d_in[2];     // (B,N)
    const float* tpoly  = (const float*)d_in[3];   // (B,N,K,2)
    float* out = (float*)d_out;                    // (B,Q,N)

    dim3 grid((Q_ + BQ - 1) / BQ, B_);             // (32, 32)
    matcher_cost_kernel<<<grid, THREADS, 0, stream>>>(logits, ppoly, labels, tpoly, out);
}